// Round 1
// baseline (68.846 us; speedup 1.0000x reference)
//
#include <hip/hip_runtime.h>

// MeanAggregator: 4 fused gather outputs.
//   out0 = mean_k features[neigh_idx[b,k]]          [B, D]
//   out1 = mean_k features[perm[neigh_idx[b,k]]]    [B, D]
//   out2 = features[nodes[b]]                       [B, D]
//   out3 = features[perm[nodes[b]]]                 [B, D]
// B=16384, K=10, D=256, features [100000, 256] f32.

constexpr int BATCH   = 16384;
constexpr int K_SAMPLE = 10;
constexpr int D_FEAT  = 256;
constexpr int ROWS_PER_BLOCK = 4;   // one wave (64 lanes) per batch row

__global__ __launch_bounds__(256)
void mean_agg_kernel(const float* __restrict__ features,
                     const int*   __restrict__ neigh_idx,
                     const int*   __restrict__ nodes,
                     const int*   __restrict__ perm,
                     float*       __restrict__ out)
{
    const int wid  = threadIdx.x >> 6;          // wave id within block
    const int lane = threadIdx.x & 63;
    const int b    = blockIdx.x * ROWS_PER_BLOCK + wid;
    if (b >= BATCH) return;
    const int d = lane * 4;                     // this lane's float4 column

    // ---- neighbor means (plain + shuffled) ----
    float4 acc  = make_float4(0.f, 0.f, 0.f, 0.f);
    float4 accs = make_float4(0.f, 0.f, 0.f, 0.f);

    #pragma unroll
    for (int k = 0; k < K_SAMPLE; ++k) {
        const int idx  = neigh_idx[b * K_SAMPLE + k];   // wave-uniform
        const int pidx = perm[idx];                     // wave-uniform
        const float4 f  = *reinterpret_cast<const float4*>(
            &features[(size_t)idx  * D_FEAT + d]);
        const float4 fs = *reinterpret_cast<const float4*>(
            &features[(size_t)pidx * D_FEAT + d]);
        acc.x  += f.x;  acc.y  += f.y;  acc.z  += f.z;  acc.w  += f.w;
        accs.x += fs.x; accs.y += fs.y; accs.z += fs.z; accs.w += fs.w;
    }

    const float inv = 1.0f / (float)K_SAMPLE;
    float4 o0 = make_float4(acc.x  * inv, acc.y  * inv, acc.z  * inv, acc.w  * inv);
    float4 o1 = make_float4(accs.x * inv, accs.y * inv, accs.z * inv, accs.w * inv);

    // ---- skip (self) gathers ----
    const int n  = nodes[b];                            // wave-uniform
    const int pn = perm[n];
    const float4 o2 = *reinterpret_cast<const float4*>(
        &features[(size_t)n  * D_FEAT + d]);
    const float4 o3 = *reinterpret_cast<const float4*>(
        &features[(size_t)pn * D_FEAT + d]);

    // ---- stores: outputs concatenated flat in return order ----
    const size_t row = (size_t)b * D_FEAT + d;
    const size_t sec = (size_t)BATCH * D_FEAT;
    *reinterpret_cast<float4*>(&out[row]            ) = o0;
    *reinterpret_cast<float4*>(&out[row +     sec]  ) = o1;
    *reinterpret_cast<float4*>(&out[row + 2 * sec]  ) = o2;
    *reinterpret_cast<float4*>(&out[row + 3 * sec]  ) = o3;
}

extern "C" void kernel_launch(void* const* d_in, const int* in_sizes, int n_in,
                              void* d_out, int out_size, void* d_ws, size_t ws_size,
                              hipStream_t stream) {
    const float* features  = (const float*)d_in[0];
    const int*   neigh_idx = (const int*)  d_in[1];
    const int*   nodes     = (const int*)  d_in[2];
    const int*   perm      = (const int*)  d_in[3];
    float*       out       = (float*)d_out;

    const int grid = BATCH / ROWS_PER_BLOCK;   // 4096 blocks x 256 threads
    mean_agg_kernel<<<grid, 256, 0, stream>>>(features, neigh_idx, nodes, perm, out);
}